// Round 11
// baseline (241.248 us; speedup 1.0000x reference)
//
#include <hip/hip_runtime.h>
#include <hip/hip_bf16.h>
#include <math.h>

#define N_   16
#define CIN  16
#define D_   32
#define H_   64
#define W_   64
#define COUT 32

#define DHW_ (D_ * H_ * W_)
#define HW_  (H_ * W_)

using frag  = __attribute__((ext_vector_type(8))) short;   // 8 bf16 = 4 VGPRs
using v16f  = __attribute__((ext_vector_type(16))) float;  // MFMA 32x32 accum

static __device__ __forceinline__ unsigned short f2bf(float f) {
  union { float f; unsigned u; } a; a.f = f;
  unsigned u = a.u;
  unsigned r = (u + 0x7fffu + ((u >> 16) & 1u)) >> 16;   // RNE
  return (unsigned short)r;
}
// Packed f32x2 -> bf16x2 (RNE), single HW instruction.
static __device__ __forceinline__ unsigned pack2(float lo, float hi) {
  unsigned r;
  asm("v_cvt_pk_bf16_f32 %0, %1, %2" : "=v"(r) : "v"(lo), "v"(hi));
  return r;
}

// mod-6 for 0 <= s6 <= 41:  s6 - 6*floor(s6*43/256)  (exact in this range).
static __device__ __forceinline__ int mod6(int s6) {
  return s6 - 6 * ((s6 * 43) >> 8);
}

// Weight prep: wt[tap][ichalf][oc][ic8] (bf16) <- w[oc][ic][tap] (fp32).
// 27*2*32*8 = 13824 elements; grid 54 x 256.
__global__ void wprep(const float* __restrict__ w, __hip_bfloat16* __restrict__ wt) {
  int i = blockIdx.x * 256 + threadIdx.x;
  int icl = i & 7, oc = (i >> 3) & 31, half = (i >> 8) & 1, tap = i >> 9;
  int ic = half * 8 + icl;
  wt[i] = __hip_bfloat16(__hip_bfloat16_raw{f2bf(w[(oc * 16 + ic) * 27 + tap])});
}

// Single fused kernel: conv3d(16->32,k3,p1) + bias + maxpool2^3 + LSE(ch) + relu.
// Block = 4 waves. Grid (wt=2, hpt=8, z=32: n=z>>1, dphalf=z&1).
// R10 vs R9 (91us; ~75% stall; convoy theory): 6-SLOT RING, ONE BARRIER/DPI.
//  - Planes 2dp+1..2dp+6 are distinct mod 6 => staged write-slots are disjoint
//    from every concurrent reader even at full 1-dpi wave skew; stale-slot
//    reuse is >=1 barrier separated. The syncA/commit/syncB critical section
//    and the entire asm prefetch machinery are deleted; staging is a plain
//    load->pack->write whose latency hides under sibling-wave TLP.
//  - Weights leave LDS (6-slot xlds = 65280 B keeps 2 blocks/CU): wprep
//    pre-transposes W into d_ws in b-frag layout; MFMA reads b-frags as
//    L2-resident global_load_dwordx4 (55 KB working set).
// Barriers/block: 15 -> 8.
__global__ __launch_bounds__(256, 2)
void conv_fused(const float* __restrict__ x,
                const __hip_bfloat16* __restrict__ wt,
                const float* __restrict__ bias,
                float* __restrict__ out) {
  // [6 slot][10 row][2 ichalf][34 wslot][8 ic] = 32640 shorts = 65280 B
  __shared__ __hip_bfloat16 xlds[6 * 10 * 2 * 34 * 8];

  const int tid = threadIdx.x;
  const int lane = tid & 63;
  const int q = tid >> 6;            // wave id
  const int m = lane & 31;
  const int hs = lane >> 5;
  const int wtb = blockIdx.x;        // 0..1
  const int hpt = blockIdx.y;        // 0..7
  const int n = blockIdx.z >> 1;
  const int dphalf = blockIdx.z & 1;

  // Per-lane bias for the 16 accum rows (row/oc = (r&3)+8*(r>>2)+4*hs).
  float bias_r[16];
  #pragma unroll
  for (int r = 0; r < 16; ++r)
    bias_r[r] = bias[(r & 3) + 8 * (r >> 2) + 4 * hs];

  // Per-lane base into the pre-transposed weights: frag(tap) = wtl[tap*512].
  const __hip_bfloat16* wtl = wt + hs * 256 + m * 8;

  const int h0 = 8 * hpt - 1;
  const int w0g = wtb * 32 - 1;
  const float* xn = x + (size_t)n * CIN * DHW_;

  // 8 uniform channel-base pointers -> SGPR pairs.
  const float* xj[8];
  #pragma unroll
  for (int j = 0; j < 8; ++j) xj[j] = xn + (size_t)j * DHW_;

  // ---- per-thread staging descriptors (decode hoisted out of the dpi loop) --
  // Task t = tid + 256k, t in [0,1360): ru = t/68, sub = t%68,
  // s = sub>>1 (w-slot 0..33), half = sub&1 (ic half), go = (ru>=10),
  // rr = ru%10 (LDS row). Only k=5 can be inactive (t>=1360 <=> tid>=80).
  int goffw[6];   // global word offset, excluding the g-plane term
  int ldsoB[6];   // LDS byte offset within one plane slot
  int go6[6];     // plane offset within the staged pair (0/1)
  bool vhw6[6];   // active && h,w in bounds (g checked per call)
  #pragma unroll
  for (int k = 0; k < 6; ++k) {
    int t = tid + 256 * k;
    int ru = t / 68;
    int sub = t - ru * 68;
    int go = (ru >= 10) ? 1 : 0;
    int rr = ru - 10 * go;
    int s = sub >> 1, half = sub & 1;
    int h = h0 + rr, gw = w0g + s;
    go6[k] = go;
    vhw6[k] = (t < 1360) && ((unsigned)h < (unsigned)H_) &&
              ((unsigned)gw < (unsigned)W_);
    // [row][half][wslot][8ic] bf16 -> byte = ((rr*2 + half)*34 + s)*16
    ldsoB[k] = ((rr * 2 + half) * 34 + s) * 16;
    goffw[k] = half * 8 * DHW_ + h * W_ + gw;
  }
  const bool act5 = (tid < 80);   // k=5 task-active mask (k<5 always active)

  // Stage planes {g0, g0+1}: load + pack + write. Target slots are disjoint
  // from all concurrent readers (6-slot ring invariant), so this needs no
  // surrounding barriers; sibling-wave TLP hides the HBM latency.
  auto stage_now = [&](int g0) {
    #pragma unroll
    for (int k = 0; k < 6; ++k) {
      int g = g0 + go6[k];
      bool v = vhw6[k] && ((unsigned)g < (unsigned)D_);
      unsigned offw = v ? (unsigned)(goffw[k] + g * HW_) : 0u;  // clamp: in-bounds
      float f[8];
      #pragma unroll
      for (int j = 0; j < 8; ++j) f[j] = xj[j][offw];
      uint4 val;
      val.x = v ? pack2(f[0], f[1]) : 0u;
      val.y = v ? pack2(f[2], f[3]) : 0u;
      val.z = v ? pack2(f[4], f[5]) : 0u;
      val.w = v ? pack2(f[6], f[7]) : 0u;
      if (k < 5 || act5)
        *(uint4*)((char*)xlds + (mod6(g + 6) * 10880 + ldsoB[k])) = val;
    }
  };

  const int dp0 = dphalf * 8;
  stage_now(2 * dp0 - 1);   // planes 2dp0-1, 2dp0
  stage_now(2 * dp0 + 1);   // planes 2dp0+1, 2dp0+2
  __syncthreads();          // prologue staging visible

  for (int dpi = 0; dpi < 8; ++dpi) {
    const int dp = dp0 + dpi;

    // ---- MFMA compute (operand-swapped: D rows = oc, cols = w) ---------------
    v16f acc[2][2];
    #pragma unroll
    for (int td = 0; td < 2; ++td)
      #pragma unroll
      for (int th = 0; th < 2; ++th)
        #pragma unroll
        for (int e = 0; e < 16; ++e) acc[td][th][e] = 0.f;

    int sj[4];
    #pragma unroll
    for (int j = 0; j < 4; ++j) sj[j] = mod6(2 * dp + 5 + j);   // (2dp-1+j) mod 6

    __builtin_amdgcn_s_setprio(1);
    #pragma unroll
    for (int kw = 0; kw < 3; ++kw) {
      frag a[4][4];   // patches [plane j = kd+td][row r = kh+th], rows 2q..2q+3
      #pragma unroll
      for (int j = 0; j < 4; ++j)
        #pragma unroll
        for (int r = 0; r < 4; ++r)
          a[j][r] = *(const frag*)
              &xlds[((sj[j] * 10 + 2 * q + r) * 2 + hs) * 272 + (kw + m) * 8];
      #pragma unroll
      for (int kd = 0; kd < 3; ++kd)
        #pragma unroll
        for (int kh = 0; kh < 3; ++kh) {
          frag b = *(const frag*)&wtl[(size_t)((kd * 3 + kh) * 3 + kw) * 512];
          #pragma unroll
          for (int td = 0; td < 2; ++td)
            #pragma unroll
            for (int th = 0; th < 2; ++th)
              acc[td][th] = __builtin_amdgcn_mfma_f32_32x32x16_bf16(
                  b, a[kd + td][kh + th], acc[td][th], 0, 0, 0);
        }
    }
    __builtin_amdgcn_s_setprio(0);

    // Stage the next pair (planes 2dp+3, 2dp+4 -> slots == planes 2dp-3, 2dp-2
    // mod 6): disjoint from this dpi's readers AND from any skewed wave's
    // reads/writes; last readers were MFMA(dpi-2), >=1 barrier ago.
    if (dpi < 7) stage_now(2 * dp + 3);

    // ---- pool + bias + LSE(oc) + relu + store (all in-register) --------------
    // Pool d (td), h (th) in-register; w via DPP quad_perm [1,0,3,2] max.
    // LSE: no max-shift (|v| bounded, fp32 exp-sum safe); hs halves combined
    // with one shfl_xor(32). Independent of staging -> scheduler overlaps the
    // stage loads' latency with this VALU tail.
    float Sh = 0.f;
    #pragma unroll
    for (int r = 0; r < 16; ++r) {
      float p = fmaxf(fmaxf(acc[0][0][r], acc[0][1][r]),
                      fmaxf(acc[1][0][r], acc[1][1][r]));
      int pi = __builtin_bit_cast(int, p);
      int qi = __builtin_amdgcn_update_dpp(pi, pi, 0xB1, 0xF, 0xF, false);
      float pw2 = fmaxf(p, __builtin_bit_cast(float, qi));
      Sh += __expf(pw2 + bias_r[r]);
    }
    float S = Sh + __shfl_xor(Sh, 32, 64);
    if (hs == 0 && (m & 1) == 0) {
      float r = fmaxf(__logf(S), 0.f);
      out[((n * 16 + dp) * 32 + 4 * hpt + q) * 32 + 16 * wtb + (m >> 1)] = r;
    }

    if (dpi < 7) __syncthreads();   // ONE barrier per dpi: commits visible
  }
}

extern "C" void kernel_launch(void* const* d_in, const int* in_sizes, int n_in,
                              void* d_out, int out_size, void* d_ws, size_t ws_size,
                              hipStream_t stream) {
  const float* x = (const float*)d_in[0];
  const float* w = (const float*)d_in[1];
  const float* b = (const float*)d_in[2];
  float* out = (float*)d_out;
  __hip_bfloat16* wt = (__hip_bfloat16*)d_ws;   // 27648 B
  wprep<<<dim3(54), dim3(256), 0, stream>>>(w, wt);
  conv_fused<<<dim3(2, 8, 32), dim3(256), 0, stream>>>(x, wt, b, out);
}

// Round 12
// 231.607 us; speedup vs baseline: 1.0416x; 1.0416x over previous
//
#include <hip/hip_runtime.h>
#include <hip/hip_bf16.h>
#include <math.h>

#define N_   16
#define CIN  16
#define D_   32
#define H_   64
#define W_   64
#define COUT 32

#define DHW_ (D_ * H_ * W_)
#define HW_  (H_ * W_)

using frag  = __attribute__((ext_vector_type(8))) short;   // 8 bf16 = 4 VGPRs
using v16f  = __attribute__((ext_vector_type(16))) float;  // MFMA 32x32 accum

static __device__ __forceinline__ unsigned short f2bf(float f) {
  union { float f; unsigned u; } a; a.f = f;
  unsigned u = a.u;
  unsigned r = (u + 0x7fffu + ((u >> 16) & 1u)) >> 16;   // RNE
  return (unsigned short)r;
}
// Packed f32x2 -> bf16x2 (RNE), single HW instruction.
static __device__ __forceinline__ unsigned pack2(float lo, float hi) {
  unsigned r;
  asm("v_cvt_pk_bf16_f32 %0, %1, %2" : "=v"(r) : "v"(lo), "v"(hi));
  return r;
}

// mod-6 for 0 <= s6 <= 41:  s6 - 6*floor(s6*43/256)  (exact in this range).
static __device__ __forceinline__ int mod6(int s6) {
  return s6 - 6 * ((s6 * 43) >> 8);
}

// Single fused kernel: conv3d(16->32,k3,p1) + bias + maxpool2^3 + LSE(ch) + relu.
// R11 vs R10 (103us REGRESSION; R9 best 91us): R10's damage was weights-in-
// global (WRITE_SIZE 1->26MB scratch spill signature + 27 L2-latency b-frag
// loads/dpi on the MFMA path, MfmaUtil 25->22). The 6-slot ring itself was
// sound. R11 keeps the ring + 1 barrier/dpi and returns weights to LDS,
// paying the LDS bill with ONE 512-thread block per CU (8 waves, same TLP
// as 2x256): x-ring [6][10][2][66][8] = 126720 B + wlds 27648 B = 154368 B.
// Former wt grid dim -> wave coord wq; ring covers full W=64 row.
// Grid (8 hpt, 32 z) = 256 blocks = exactly 1/CU.
__global__ __launch_bounds__(512, 2)
void conv_fused(const float* __restrict__ x,
                const float* __restrict__ w,
                const float* __restrict__ bias,
                float* __restrict__ out) {
  // [6 slot][10 row][2 ichalf][66 wslot][8 ic] = 63360 shorts = 126720 B
  __shared__ __hip_bfloat16 xlds[6 * 10 * 2 * 66 * 8];
  // [27 tap][2 ichalf][32 oc][8 ic]            = 13824 shorts =  27648 B
  __shared__ __hip_bfloat16 wlds[27 * 2 * 32 * 8];

  const int tid = threadIdx.x;
  const int lane = tid & 63;
  const int wv = tid >> 6;           // wave id 0..7
  const int q = wv & 3;              // h-row group (rows 2q..2q+3)
  const int wq = wv >> 2;            // w half-tile 0..1
  const int m = lane & 31;
  const int hs = lane >> 5;
  const int hpt = blockIdx.x;        // 0..7
  const int n = blockIdx.y >> 1;
  const int dphalf = blockIdx.y & 1;

  // ---- stage weights: wlds[tap][ic>>3][oc][ic&7] <- bf16(w[oc][ic][tap]) ----
  for (int i = tid; i < 27 * 32 * 16; i += 512) {
    int ic = i & 15;
    int t2 = i >> 4;
    int oc = t2 & 31;
    int tap = t2 >> 5;
    wlds[((tap * 2 + (ic >> 3)) * 32 + oc) * 8 + (ic & 7)] =
        __hip_bfloat16(__hip_bfloat16_raw{f2bf(w[(oc * 16 + ic) * 27 + tap])});
  }

  // Per-lane bias for the 16 accum rows (row/oc = (r&3)+8*(r>>2)+4*hs).
  float bias_r[16];
  #pragma unroll
  for (int r = 0; r < 16; ++r)
    bias_r[r] = bias[(r & 3) + 8 * (r >> 2) + 4 * hs];

  const int h0 = 8 * hpt - 1;
  const float* xn = x + (size_t)n * CIN * DHW_;

  // 8 uniform channel-base pointers -> SGPR pairs.
  const float* xj[8];
  #pragma unroll
  for (int j = 0; j < 8; ++j) xj[j] = xn + (size_t)j * DHW_;

  // ---- per-thread staging descriptors (decode hoisted out of the dpi loop) --
  // Task t = tid + 512k, t in [0,2640): ru = t/132 (row of the plane pair),
  // sub = t%132: s = sub>>1 (w-slot 0..65), half = sub&1 (ic half),
  // go = (ru>=10), rr = ru%10. 2640 = 5*512 + 80 -> only k=5 partial (tid<80).
  int goffw[6];   // global word offset, excluding the g-plane term
  int ldsoB[6];   // LDS byte offset within one plane slot
  int go6[6];     // plane offset within the staged pair (0/1)
  bool vhw6[6];   // active && h,w in bounds (g checked per call)
  #pragma unroll
  for (int k = 0; k < 6; ++k) {
    int t = tid + 512 * k;
    int ru = t / 132;
    int sub = t - ru * 132;
    int go = (ru >= 10) ? 1 : 0;
    int rr = ru - 10 * go;
    int s = sub >> 1, half = sub & 1;
    int h = h0 + rr, gw = s - 1;
    go6[k] = go;
    vhw6[k] = (t < 2640) && ((unsigned)h < (unsigned)H_) &&
              ((unsigned)gw < (unsigned)W_);
    // [row][half][wslot 66][8ic] bf16 -> byte = ((rr*2 + half)*66 + s)*16
    ldsoB[k] = ((rr * 2 + half) * 66 + s) * 16;
    goffw[k] = half * 8 * DHW_ + h * W_ + gw;
  }
  const bool act5 = (tid < 80);   // k=5 task-active mask (k<5 always active)

  // Stage planes {g0, g0+1}: load + pack + write. Ring invariant: planes
  // 2dp-1..2dp+4 are 6 consecutive ints -> distinct mod 6, so write slots are
  // disjoint from every reader between consecutive barriers. Plain loads;
  // sibling-wave TLP hides the HBM latency.
  auto stage_now = [&](int g0) {
    #pragma unroll
    for (int k = 0; k < 6; ++k) {
      int g = g0 + go6[k];
      bool v = vhw6[k] && ((unsigned)g < (unsigned)D_);
      unsigned offw = v ? (unsigned)(goffw[k] + g * HW_) : 0u;  // clamp: in-bounds
      float f[8];
      #pragma unroll
      for (int j = 0; j < 8; ++j) f[j] = xj[j][offw];
      uint4 val;
      val.x = v ? pack2(f[0], f[1]) : 0u;
      val.y = v ? pack2(f[2], f[3]) : 0u;
      val.z = v ? pack2(f[4], f[5]) : 0u;
      val.w = v ? pack2(f[6], f[7]) : 0u;
      if (k < 5 || act5)
        *(uint4*)((char*)xlds + (mod6(g + 6) * 21120 + ldsoB[k])) = val;
    }
  };

  const int dp0 = dphalf * 8;
  stage_now(2 * dp0 - 1);   // planes 2dp0-1, 2dp0
  stage_now(2 * dp0 + 1);   // planes 2dp0+1, 2dp0+2
  __syncthreads();          // prologue staging + weights visible

  for (int dpi = 0; dpi < 8; ++dpi) {
    const int dp = dp0 + dpi;

    // ---- MFMA compute (operand-swapped: D rows = oc, cols = w) ---------------
    v16f acc[2][2];
    #pragma unroll
    for (int td = 0; td < 2; ++td)
      #pragma unroll
      for (int th = 0; th < 2; ++th)
        #pragma unroll
        for (int e = 0; e < 16; ++e) acc[td][th][e] = 0.f;

    int sj[4];
    #pragma unroll
    for (int j = 0; j < 4; ++j) sj[j] = mod6(2 * dp + 5 + j);   // (2dp-1+j) mod 6

    __builtin_amdgcn_s_setprio(1);
    #pragma unroll
    for (int kw = 0; kw < 3; ++kw) {
      frag a[4][4];   // patches [plane j = kd+td][row r = kh+th], rows 2q..2q+3
      #pragma unroll
      for (int j = 0; j < 4; ++j)
        #pragma unroll
        for (int r = 0; r < 4; ++r)
          a[j][r] = *(const frag*)
              &xlds[((sj[j] * 10 + 2 * q + r) * 2 + hs) * 528 +
                    (kw + m + 32 * wq) * 8];
      #pragma unroll
      for (int kd = 0; kd < 3; ++kd)
        #pragma unroll
        for (int kh = 0; kh < 3; ++kh) {
          frag b = *(const frag*)
              &wlds[(((kd * 3 + kh) * 3 + kw) * 2 + hs) * 256 + m * 8];
          #pragma unroll
          for (int td = 0; td < 2; ++td)
            #pragma unroll
            for (int th = 0; th < 2; ++th)
              acc[td][th] = __builtin_amdgcn_mfma_f32_32x32x16_bf16(
                  b, a[kd + td][kh + th], acc[td][th], 0, 0, 0);
        }
    }
    __builtin_amdgcn_s_setprio(0);

    // Stage the next pair (planes 2dp+3, 2dp+4): slots disjoint from all
    // readers this side of the barrier (ring invariant above).
    if (dpi < 7) stage_now(2 * dp + 3);

    // ---- pool + bias + LSE(oc) + relu + store (all in-register) --------------
    // Pool d (td), h (th) in-register; w via DPP quad_perm [1,0,3,2] max.
    // LSE: no max-shift (|v| bounded, fp32 exp-sum safe); hs halves combined
    // with one shfl_xor(32). Independent of staging -> overlaps its latency.
    float Sh = 0.f;
    #pragma unroll
    for (int r = 0; r < 16; ++r) {
      float p = fmaxf(fmaxf(acc[0][0][r], acc[0][1][r]),
                      fmaxf(acc[1][0][r], acc[1][1][r]));
      int pi = __builtin_bit_cast(int, p);
      int qi = __builtin_amdgcn_update_dpp(pi, pi, 0xB1, 0xF, 0xF, false);
      float pw2 = fmaxf(p, __builtin_bit_cast(float, qi));
      Sh += __expf(pw2 + bias_r[r]);
    }
    float S = Sh + __shfl_xor(Sh, 32, 64);
    if (hs == 0 && (m & 1) == 0) {
      float r = fmaxf(__logf(S), 0.f);
      out[((n * 16 + dp) * 32 + 4 * hpt + q) * 32 + 16 * wq + (m >> 1)] = r;
    }

    if (dpi < 7) __syncthreads();   // ONE barrier per dpi: commits visible
  }
}

extern "C" void kernel_launch(void* const* d_in, const int* in_sizes, int n_in,
                              void* d_out, int out_size, void* d_ws, size_t ws_size,
                              hipStream_t stream) {
  const float* x = (const float*)d_in[0];
  const float* w = (const float*)d_in[1];
  const float* b = (const float*)d_in[2];
  float* out = (float*)d_out;
  conv_fused<<<dim3(8, 32), dim3(512), 0, stream>>>(x, w, b, out);
}